// Round 11
// baseline (399.424 us; speedup 1.0000x reference)
//
#include <hip/hip_runtime.h>

#define NTOK 343
#define NPAD 352
#define DIM 384
#define NHEAD 12
#define HDIM 32
#define NWIN 64
#define BATCH 128
#define SCALE 0.17677669529663687f
#define NN 117649   // 343*343
#define MG 88       // NPAD/4 m-groups
#define GSTRIDE 1372  // NTOK*4 floats per m-group

typedef __attribute__((ext_vector_type(8))) short bf16x8;
typedef __attribute__((ext_vector_type(4))) short bf16x4;
typedef __attribute__((ext_vector_type(4))) float f32x4;
typedef __attribute__((ext_vector_type(4))) int i32x4;

static __device__ inline short f2bf(float f) {
  union { float f; unsigned u; } v; v.f = f;
  unsigned r = v.u + 0x7fffu + ((v.u >> 16) & 1u);
  return (short)(r >> 16);
}
static __device__ inline float bf2f(short s) {
  union { unsigned u; float f; } v; v.u = ((unsigned)(unsigned short)s) << 16;
  return v.f;
}
// RTNE pack (proven path, non-hot kernels)
static __device__ inline int pack2(float lo, float hi) {
  return (int)((unsigned)(unsigned short)f2bf(lo) |
               ((unsigned)(unsigned short)f2bf(hi) << 16));
}
// fast pack: round-to-nearest (+0x8000) then v_perm grabs the two high halves.
// 3 VALU ops vs ~11. Ties round away instead of to-even (<=0.5 ulp, same bound).
static __device__ inline int pack2rn(float lo, float hi) {
  union { float f; unsigned u; } a, b;
  a.f = lo; b.f = hi;
  unsigned au = a.u + 0x8000u;
  unsigned bu = b.u + 0x8000u;
  return (int)__builtin_amdgcn_perm(bu, au, 0x07060302u);
}
static __device__ inline short f2bfrn(float f) {
  union { float f; unsigned u; } v; v.f = f;
  return (short)((v.u + 0x8000u) >> 16);
}

#define MFMA16(a, b, c) __builtin_amdgcn_mfma_f32_16x16x32_bf16((a), (b), (c), 0, 0, 0)

// ---- kernel 0a: bias_q4[h][g][q][r] = table[rpi[q][g*4+r]][h], pad=-1e30 ----
__global__ __launch_bounds__(256) void bias_pk_kernel(
    const float* __restrict__ table, const int* __restrict__ rpi,
    float* __restrict__ bias_q4) {
  int idx = blockIdx.x * 256 + threadIdx.x;
  const int total = NHEAD * MG * NTOK * 4;
  if (idx >= total) return;
  int r = idx & 3;
  int t = idx >> 2;
  int q = t % NTOK;
  int u = t / NTOK;
  int g = u % MG;
  int h = u / MG;
  int m = g * 4 + r;
  bias_q4[idx] = (m < NTOK) ? table[rpi[q * NTOK + m] * NHEAD + h] : -1e30f;
}

// ---- kernel 0b: mask_q4[w][g][q][r] = mask[w][q][g*4+r], pad=0 --------------
__global__ __launch_bounds__(256) void mask_pk_kernel(
    const float* __restrict__ in, float* __restrict__ mask_q4) {
  int idx = blockIdx.x * 256 + threadIdx.x;
  const int total = NWIN * MG * NTOK * 4;
  if (idx >= total) return;
  int r = idx & 3;
  int t = idx >> 2;
  int q = t % NTOK;
  int u = t / NTOK;
  int g = u % MG;
  int w = u / MG;
  int m = g * 4 + r;
  mask_q4[idx] = (m < NTOK) ? in[(size_t)w * NN + q * NTOK + m] : 0.0f;
}

// ---- kernel 0c: skip f32 -> bf16 (A-operand for kv_proj) -------------------
__global__ __launch_bounds__(256) void cvt_skip_kernel(
    const float* __restrict__ in, short* __restrict__ out, int n8) {
  int i = blockIdx.x * 256 + threadIdx.x;
  if (i >= n8) return;
  f32x4 a = *(const f32x4*)(in + (size_t)i * 8);
  f32x4 b = *(const f32x4*)(in + (size_t)i * 8 + 4);
  bf16x8 o;
#pragma unroll
  for (int j = 0; j < 4; ++j) {
    o[j] = f2bf(a[j]);
    o[j + 4] = f2bf(b[j]);
  }
  *(bf16x8*)(out + (size_t)i * 8) = o;
}

// ---------- kernel 1: kv = skip_bf @ w_kv^T + b_kv -> K_ws/V_ws (bf16) ------
__global__ __launch_bounds__(256) void kv_proj_kernel(
    const short* __restrict__ Xbf, const float* __restrict__ W,
    const float* __restrict__ bkv, short* __restrict__ Kws,
    short* __restrict__ Vws) {
  __shared__ short As[128][40];
  __shared__ short Bs[128][40];
  const int tid = threadIdx.x;
  const int n0 = blockIdx.x * 128;
  const int m0 = blockIdx.y * 128;
  const int lane = tid & 63;
  const int wave = tid >> 6;
  const int wm = (wave >> 1) * 64;
  const int wn = (wave & 1) * 64;
  const int lr = lane & 15;
  const int lk = (lane >> 4) * 8;
  const int c4 = (tid & 7) * 4;
  const int rbase = tid >> 3;
  const int arow = tid >> 2;        // 0..63
  const int acol8 = (tid & 3) * 8;  // 0,8,16,24
  const f32x4 zero4 = {0.f, 0.f, 0.f, 0.f};

  f32x4 acc[4][4];
#pragma unroll
  for (int m = 0; m < 4; ++m)
#pragma unroll
    for (int n = 0; n < 4; ++n) acc[m][n] = zero4;

  for (int kk = 0; kk < 12; ++kk) {
    __syncthreads();
    // A: direct bf16x8 copy (no conversion)
    *(bf16x8*)(&As[arow][acol8]) =
        *(const bf16x8*)(Xbf + (size_t)(m0 + arow) * DIM + kk * 32 + acol8);
    *(bf16x8*)(&As[arow + 64][acol8]) =
        *(const bf16x8*)(Xbf + (size_t)(m0 + arow + 64) * DIM + kk * 32 + acol8);
    // B: f32 -> bf16 (W is small, L2-resident)
#pragma unroll
    for (int i = 0; i < 4; ++i) {
      int row = rbase + i * 32;
      f32x4 v = *(const f32x4*)(W + (size_t)(n0 + row) * DIM + kk * 32 + c4);
      bf16x4 s4;
#pragma unroll
      for (int j = 0; j < 4; ++j) s4[j] = f2bf(v[j]);
      *(bf16x4*)(&Bs[row][c4]) = s4;
    }
    __syncthreads();
    bf16x8 af[4], bf[4];
#pragma unroll
    for (int m = 0; m < 4; ++m) af[m] = *(const bf16x8*)(&As[wm + m * 16 + lr][lk]);
#pragma unroll
    for (int n = 0; n < 4; ++n) bf[n] = *(const bf16x8*)(&Bs[wn + n * 16 + lr][lk]);
#pragma unroll
    for (int m = 0; m < 4; ++m)
#pragma unroll
      for (int n = 0; n < 4; ++n) acc[m][n] = MFMA16(af[m], bf[n], acc[m][n]);
  }

  const int rq = (lane >> 4) * 4;
#pragma unroll
  for (int n = 0; n < 4; ++n) {
    int gcol = n0 + wn + n * 16 + lr;
    float bias = bkv[gcol];
    int c = (gcol >= DIM) ? (gcol - DIM) : gcol;  // gcol % 384
    int h = c >> 5;
    int hd = c & 31;
    short* dst = (gcol < DIM) ? Kws : Vws;
#pragma unroll
    for (int m = 0; m < 4; ++m) {
#pragma unroll
      for (int r = 0; r < 4; ++r) {
        int grow = m0 + wm + m * 16 + rq + r;
        int bb = grow / NTOK;
        int tok = grow - bb * NTOK;
        dst[(((size_t)bb * NHEAD + h) * NTOK + tok) * HDIM + hd] =
            f2bf(acc[m][n][r] + bias);
      }
    }
  }
}

// ---------- kernel 2: fused attention per (b, h) — swapped-QK^T form --------
// 512 threads / 8 waves: same 51.2KB LDS -> 3 blocks/CU -> 24 waves/CU
// (2x TLP vs 256-thread). Win-grouped XCD swizzle; f32x4 bias/mask loads;
// perm-based bf16 pack (3 VALU); +pos fused; setprio on MFMA clusters.
__global__ __launch_bounds__(512, 3) void attn_kernel(
    const float* __restrict__ x_up, const float* __restrict__ mask_q4,
    const float* __restrict__ bias_q4, const short* __restrict__ Kws,
    const short* __restrict__ Vws, const float* __restrict__ pos,
    short* __restrict__ attn_out) {
  __shared__ short Ksm[NPAD][40];      // K[key][ch], row stride 80B
  __shared__ short Vp[HDIM][NPAD + 8]; // V^T[ch][pi(key)], row stride 720B
  const int bid = blockIdx.x;
  const int xcd = bid & 7;
  const int jj = bid >> 3;                 // 0..191
  const int win = xcd * 8 + jj / 24;       // 0..63, pinned to xcd
  const int rep = jj - (jj / 24) * 24;     // 0..23
  const int h = rep % NHEAD;
  const int b = win + ((rep >= NHEAD) ? 64 : 0);
  const int tid = threadIdx.x;
  const int wave = tid >> 6;               // 0..7
  const int lane = tid & 63;
  const int lr = lane & 15;
  const int lg = lane >> 4;
  const int koff = lg * 8;
  const f32x4 zero4 = {0.f, 0.f, 0.f, 0.f};

  const short* Kb = Kws + ((size_t)b * NHEAD + h) * NTOK * HDIM;
  const short* Vb = Vws + ((size_t)b * NHEAD + h) * NTOK * HDIM;
  {
    const int c8 = (tid & 3) * 8;
    const int rb = tid >> 2;   // 0..127
    const bf16x8 z8 = {0, 0, 0, 0, 0, 0, 0, 0};
#pragma unroll
    for (int r0 = 0; r0 < 384; r0 += 128) {
      int row = r0 + rb;
      if (row < NPAD) {
        bf16x8 kv = z8;
        if (row < NTOK) kv = *(const bf16x8*)(Kb + row * HDIM + c8);
        *(bf16x8*)(&Ksm[row][c8]) = kv;
      }
    }
#pragma unroll
    for (int r0 = 0; r0 < 384; r0 += 128) {
      int row = r0 + rb;
      if (row < NPAD) {
        bf16x8 vv = z8;
        if (row < NTOK) vv = *(const bf16x8*)(Vb + row * HDIM + c8);
        // pi(row): k-slot = ((m&16)>>2) | ((m&12)<<1) | (m&3) within 32-block
        int p = (row & ~31) | ((row & 12) << 1) | ((row & 16) >> 2) | (row & 3);
#pragma unroll
        for (int i = 0; i < 8; ++i) Vp[c8 + i][p] = vv[i];
      }
    }
  }
  __syncthreads();

  for (int qt = 0; qt < 3; ++qt) {
    const int q0 = qt * 128 + wave * 16;
    if (q0 >= NTOK) continue;
    const int qn = q0 + lr;
    const int qidx = (qn < NTOK) ? qn : (NTOK - 1);
    // Q B-frag: col=q=lr, k = channel 8*lg+i (clamped row; invalid cols unused)
    bf16x8 qf;
    {
      const float* qp = x_up + ((size_t)b * NTOK + qidx) * DIM + h * HDIM + koff;
      f32x4 v0 = *(const f32x4*)qp;
      f32x4 v1 = *(const f32x4*)(qp + 4);
#pragma unroll
      for (int i = 0; i < 4; ++i) {
        qf[i] = f2bfrn(v0[i] * SCALE);
        qf[i + 4] = f2bfrn(v1[i] * SCALE);
      }
    }
    // S^T tiles: s[j] = K_j * Q   (A=K: row=key=lr, k=ch; B=Q)
    f32x4 s[22];
    __builtin_amdgcn_s_setprio(1);
#pragma unroll
    for (int j = 0; j < 22; ++j) {
      bf16x8 kf = *(const bf16x8*)(&Ksm[j * 16 + lr][koff]);
      s[j] = MFMA16(kf, qf, zero4);
    }
    __builtin_amdgcn_s_setprio(0);
    // softmax over m: vector bias+mask add (f32x4 loads, pad handles tail),
    // row max (2 shfls), exp, sum (2 shfls), normalize before bf16 pack.
    const float* bq = bias_q4 + (size_t)h * MG * GSTRIDE + (size_t)lg * GSTRIDE +
                      qidx * 4;
    const float* mq = mask_q4 + (size_t)win * MG * GSTRIDE + (size_t)lg * GSTRIDE +
                      qidx * 4;
    float mx = -1e30f;
#pragma unroll
    for (int j = 0; j < 22; ++j) {
      f32x4 bv = *(const f32x4*)(bq + (size_t)j * 4 * GSTRIDE);
      f32x4 mv = *(const f32x4*)(mq + (size_t)j * 4 * GSTRIDE);
      s[j] += bv + mv;
#pragma unroll
      for (int r = 0; r < 4; ++r) mx = fmaxf(mx, s[j][r]);
    }
    mx = fmaxf(mx, __shfl_xor(mx, 16));
    mx = fmaxf(mx, __shfl_xor(mx, 32));
    float sum = 0.f;
#pragma unroll
    for (int j = 0; j < 22; ++j) {
#pragma unroll
      for (int r = 0; r < 4; ++r) {
        float p = __expf(s[j][r] - mx);
        s[j][r] = p;
        sum += p;
      }
    }
    sum += __shfl_xor(sum, 16);
    sum += __shfl_xor(sum, 32);
    const float inv = 1.0f / sum;
    i32x4 up4[11];
#pragma unroll
    for (int j = 0; j < 22; ++j) {
      up4[j >> 1][(j & 1) * 2 + 0] = pack2rn(s[j][0] * inv, s[j][1] * inv);
      up4[j >> 1][(j & 1) * 2 + 1] = pack2rn(s[j][2] * inv, s[j][3] * inv);
    }

    // O^T = V^T_pi * P : A-frag from Vp (b128), B-frag = packed P registers
    f32x4 o0 = zero4;
    f32x4 o1 = zero4;
    __builtin_amdgcn_s_setprio(1);
#pragma unroll
    for (int kt = 0; kt < 11; ++kt) {
      bf16x8 pf = __builtin_bit_cast(bf16x8, up4[kt]);
      bf16x8 a0 = *(const bf16x8*)(&Vp[lr][kt * 32 + koff]);
      bf16x8 a1 = *(const bf16x8*)(&Vp[16 + lr][kt * 32 + koff]);
      o0 = MFMA16(a0, pf, o0);
      o1 = MFMA16(a1, pf, o1);
    }
    __builtin_amdgcn_s_setprio(0);
    // lane holds O[q=lr][d = 4*lg + r (+16)]; O already normalized (P*inv).
    // Add pos_embed (fused), pack+store.
    if (qn < NTOK) {
      const float* pp = pos + ((size_t)b * NTOK + qn) * DIM + h * HDIM + 4 * lg;
      f32x4 p0 = *(const f32x4*)pp;
      f32x4 p1 = *(const f32x4*)(pp + 16);
      short* op = attn_out + ((size_t)b * NTOK + qn) * DIM + h * HDIM + 4 * lg;
      *(int*)(op + 0) = pack2rn(o0[0] + p0[0], o0[1] + p0[1]);
      *(int*)(op + 2) = pack2rn(o0[2] + p0[2], o0[3] + p0[3]);
      *(int*)(op + 16) = pack2rn(o1[0] + p1[0], o1[1] + p1[1]);
      *(int*)(op + 18) = pack2rn(o1[2] + p1[2], o1[3] + p1[3]);
    }
  }
}

// ---------- kernel 3: out = Xa @ w_proj^T + b_proj (Xa = attn+pos, bf16) ----
__global__ __launch_bounds__(256) void out_proj_kernel(
    const short* __restrict__ Xa, const float* __restrict__ W,
    const float* __restrict__ bpr, float* __restrict__ out) {
  __shared__ short As[128][40];
  __shared__ short Bs[128][40];
  const int tid = threadIdx.x;
  const int n0 = blockIdx.x * 128;
  const int m0 = blockIdx.y * 128;
  const int lane = tid & 63;
  const int wave = tid >> 6;
  const int wm = (wave >> 1) * 64;
  const int wn = (wave & 1) * 64;
  const int lr = lane & 15;
  const int lk = (lane >> 4) * 8;
  const int c4 = (tid & 7) * 4;
  const int rbase = tid >> 3;
  const int arow = tid >> 2;
  const int acol8 = (tid & 3) * 8;
  const f32x4 zero4 = {0.f, 0.f, 0.f, 0.f};

  f32x4 acc[4][4];
#pragma unroll
  for (int m = 0; m < 4; ++m)
#pragma unroll
    for (int n = 0; n < 4; ++n) acc[m][n] = zero4;

  for (int kk = 0; kk < 12; ++kk) {
    __syncthreads();
    *(bf16x8*)(&As[arow][acol8]) =
        *(const bf16x8*)(Xa + (size_t)(m0 + arow) * DIM + kk * 32 + acol8);
    *(bf16x8*)(&As[arow + 64][acol8]) =
        *(const bf16x8*)(Xa + (size_t)(m0 + arow + 64) * DIM + kk * 32 + acol8);
#pragma unroll
    for (int i = 0; i < 4; ++i) {
      int row = rbase + i * 32;
      f32x4 v = *(const f32x4*)(W + (size_t)(n0 + row) * DIM + kk * 32 + c4);
      bf16x4 s4;
#pragma unroll
      for (int j = 0; j < 4; ++j) s4[j] = f2bf(v[j]);
      *(bf16x4*)(&Bs[row][c4]) = s4;
    }
    __syncthreads();
    bf16x8 af[4], bf[4];
#pragma unroll
    for (int m = 0; m < 4; ++m) af[m] = *(const bf16x8*)(&As[wm + m * 16 + lr][lk]);
#pragma unroll
    for (int n = 0; n < 4; ++n) bf[n] = *(const bf16x8*)(&Bs[wn + n * 16 + lr][lk]);
#pragma unroll
    for (int m = 0; m < 4; ++m)
#pragma unroll
      for (int n = 0; n < 4; ++n) acc[m][n] = MFMA16(af[m], bf[n], acc[m][n]);
  }

  const int rq = (lane >> 4) * 4;
#pragma unroll
  for (int n = 0; n < 4; ++n) {
    int gcol = n0 + wn + n * 16 + lr;
    float bias = bpr[gcol];
#pragma unroll
    for (int m = 0; m < 4; ++m) {
#pragma unroll
      for (int r = 0; r < 4; ++r) {
        int grow = m0 + wm + m * 16 + rq + r;
        out[(size_t)grow * DIM + gcol] = acc[m][n][r] + bias;
      }
    }
  }
}

extern "C" void kernel_launch(void* const* d_in, const int* in_sizes, int n_in,
                              void* d_out, int out_size, void* d_ws, size_t ws_size,
                              hipStream_t stream) {
  const float* skip = (const float*)d_in[0];
  const float* x_up = (const float*)d_in[1];
  const float* pos = (const float*)d_in[2];
  const float* mask = (const float*)d_in[3];
  const float* w_kv = (const float*)d_in[4];
  const float* b_kv = (const float*)d_in[5];
  const float* w_proj = (const float*)d_in[6];
  const float* b_proj = (const float*)d_in[7];
  const float* bias_table = (const float*)d_in[8];
  const int* rpi = (const int*)d_in[9];
  float* out = (float*)d_out;

  char* ws = (char*)d_ws;
  const size_t kv_bytes = (size_t)BATCH * NHEAD * NTOK * HDIM * 2;   // 33,718,272
  const size_t bias_bytes = (size_t)NHEAD * MG * NTOK * 4 * 4;       //  5,795,328
  const size_t mask_bytes = (size_t)NWIN * MG * NTOK * 4 * 4;        // 30,908,416
  short* Kws = (short*)ws;
  short* Vws = (short*)(ws + kv_bytes);
  float* bias_q4 = (float*)(ws + 2 * kv_bytes);
  float* mask_q4 = (float*)(ws + 2 * kv_bytes + bias_bytes);
  // skip_bf and attn_ws alias: cvt_skip->kv_proj finish before attn writes it
  short* skip_bf = (short*)(ws + 2 * kv_bytes + bias_bytes + mask_bytes);
  short* attn_ws = skip_bf;

  const int bias_total = NHEAD * MG * NTOK * 4;
  const int mask_total = NWIN * MG * NTOK * 4;
  const int n8 = BATCH * NTOK * DIM / 8;  // 2,107,392
  bias_pk_kernel<<<dim3((bias_total + 255) / 256), dim3(256), 0, stream>>>(
      bias_table, rpi, bias_q4);
  mask_pk_kernel<<<dim3((mask_total + 255) / 256), dim3(256), 0, stream>>>(
      mask, mask_q4);
  cvt_skip_kernel<<<dim3((n8 + 255) / 256), dim3(256), 0, stream>>>(
      skip, skip_bf, n8);
  kv_proj_kernel<<<dim3(6, 343), dim3(256), 0, stream>>>(skip_bf, w_kv, b_kv,
                                                         Kws, Vws);
  attn_kernel<<<dim3(BATCH * NHEAD), dim3(512), 0, stream>>>(
      x_up, mask_q4, bias_q4, Kws, Vws, pos, attn_ws);
  out_proj_kernel<<<dim3(3, 343), dim3(256), 0, stream>>>(attn_ws, w_proj,
                                                          b_proj, out);
}

// Round 12
// 288.884 us; speedup vs baseline: 1.3826x; 1.3826x over previous
//
#include <hip/hip_runtime.h>

#define NTOK 343
#define NPAD 352
#define DIM 384
#define NHEAD 12
#define HDIM 32
#define NWIN 64
#define BATCH 128
#define SCALE 0.17677669529663687f
#define NN 117649   // 343*343
#define MG 88       // NPAD/4 m-groups
#define GSTRIDE 1372  // NTOK*4 elems per m-group

typedef __attribute__((ext_vector_type(8))) short bf16x8;
typedef __attribute__((ext_vector_type(4))) short bf16x4;
typedef __attribute__((ext_vector_type(4))) float f32x4;
typedef __attribute__((ext_vector_type(4))) int i32x4;

static __device__ inline short f2bf(float f) {
  union { float f; unsigned u; } v; v.f = f;
  unsigned r = v.u + 0x7fffu + ((v.u >> 16) & 1u);
  return (short)(r >> 16);
}
static __device__ inline float bf2f(short s) {
  union { unsigned u; float f; } v; v.u = ((unsigned)(unsigned short)s) << 16;
  return v.f;
}
// RTNE pack (prep kernels)
static __device__ inline int pack2(float lo, float hi) {
  return (int)((unsigned)(unsigned short)f2bf(lo) |
               ((unsigned)(unsigned short)f2bf(hi) << 16));
}
// fast pack: +0x8000 round-to-nearest, v_perm grabs the two high halves.
// 3 VALU ops; proven numerically identical-at-threshold in R11 (absmax 0.0156).
static __device__ inline int pack2rn(float lo, float hi) {
  union { float f; unsigned u; } a, b;
  a.f = lo; b.f = hi;
  unsigned au = a.u + 0x8000u;
  unsigned bu = b.u + 0x8000u;
  return (int)__builtin_amdgcn_perm(bu, au, 0x07060302u);
}
static __device__ inline short f2bfrn(float f) {
  union { float f; unsigned u; } v; v.f = f;
  return (short)((v.u + 0x8000u) >> 16);
}

#define MFMA16(a, b, c) __builtin_amdgcn_mfma_f32_16x16x32_bf16((a), (b), (c), 0, 0, 0)

// ---- kernel 0a: bias_b4[h][g][q][r] = bf16(table[rpi[q][g*4+r]][h]), pad -1e30
__global__ __launch_bounds__(256) void bias_pk_kernel(
    const float* __restrict__ table, const int* __restrict__ rpi,
    short* __restrict__ bias_b4) {
  int idx = blockIdx.x * 256 + threadIdx.x;
  const int total = NHEAD * MG * NTOK * 4;
  if (idx >= total) return;
  int r = idx & 3;
  int t = idx >> 2;
  int q = t % NTOK;
  int u = t / NTOK;
  int g = u % MG;
  int h = u / MG;
  int m = g * 4 + r;
  bias_b4[idx] = (m < NTOK) ? f2bf(table[rpi[q * NTOK + m] * NHEAD + h]) : f2bf(-1e30f);
}

// ---- kernel 0b: mask_b4[w][g][q][r] = bf16(mask[w][q][g*4+r]), pad=0 --------
__global__ __launch_bounds__(256) void mask_pk_kernel(
    const float* __restrict__ in, short* __restrict__ mask_b4) {
  int idx = blockIdx.x * 256 + threadIdx.x;
  const int total = NWIN * MG * NTOK * 4;
  if (idx >= total) return;
  int r = idx & 3;
  int t = idx >> 2;
  int q = t % NTOK;
  int u = t / NTOK;
  int g = u % MG;
  int w = u / MG;
  int m = g * 4 + r;
  mask_b4[idx] = (m < NTOK) ? f2bf(in[(size_t)w * NN + q * NTOK + m]) : 0;
}

// ---- kernel 0c: skip f32 -> bf16 (A-operand for kv_proj) -------------------
__global__ __launch_bounds__(256) void cvt_skip_kernel(
    const float* __restrict__ in, short* __restrict__ out, int n8) {
  int i = blockIdx.x * 256 + threadIdx.x;
  if (i >= n8) return;
  f32x4 a = *(const f32x4*)(in + (size_t)i * 8);
  f32x4 b = *(const f32x4*)(in + (size_t)i * 8 + 4);
  bf16x8 o;
#pragma unroll
  for (int j = 0; j < 4; ++j) {
    o[j] = f2bf(a[j]);
    o[j + 4] = f2bf(b[j]);
  }
  *(bf16x8*)(out + (size_t)i * 8) = o;
}

// ---------- kernel 1: kv = skip_bf @ w_kv^T + b_kv -> K_ws/V_ws (bf16) ------
__global__ __launch_bounds__(256) void kv_proj_kernel(
    const short* __restrict__ Xbf, const float* __restrict__ W,
    const float* __restrict__ bkv, short* __restrict__ Kws,
    short* __restrict__ Vws) {
  __shared__ short As[128][40];
  __shared__ short Bs[128][40];
  const int tid = threadIdx.x;
  const int n0 = blockIdx.x * 128;
  const int m0 = blockIdx.y * 128;
  const int lane = tid & 63;
  const int wave = tid >> 6;
  const int wm = (wave >> 1) * 64;
  const int wn = (wave & 1) * 64;
  const int lr = lane & 15;
  const int lk = (lane >> 4) * 8;
  const int c4 = (tid & 7) * 4;
  const int rbase = tid >> 3;
  const int arow = tid >> 2;        // 0..63
  const int acol8 = (tid & 3) * 8;  // 0,8,16,24
  const f32x4 zero4 = {0.f, 0.f, 0.f, 0.f};

  f32x4 acc[4][4];
#pragma unroll
  for (int m = 0; m < 4; ++m)
#pragma unroll
    for (int n = 0; n < 4; ++n) acc[m][n] = zero4;

  for (int kk = 0; kk < 12; ++kk) {
    __syncthreads();
    *(bf16x8*)(&As[arow][acol8]) =
        *(const bf16x8*)(Xbf + (size_t)(m0 + arow) * DIM + kk * 32 + acol8);
    *(bf16x8*)(&As[arow + 64][acol8]) =
        *(const bf16x8*)(Xbf + (size_t)(m0 + arow + 64) * DIM + kk * 32 + acol8);
#pragma unroll
    for (int i = 0; i < 4; ++i) {
      int row = rbase + i * 32;
      f32x4 v = *(const f32x4*)(W + (size_t)(n0 + row) * DIM + kk * 32 + c4);
      bf16x4 s4;
#pragma unroll
      for (int j = 0; j < 4; ++j) s4[j] = f2bf(v[j]);
      *(bf16x4*)(&Bs[row][c4]) = s4;
    }
    __syncthreads();
    bf16x8 af[4], bf[4];
#pragma unroll
    for (int m = 0; m < 4; ++m) af[m] = *(const bf16x8*)(&As[wm + m * 16 + lr][lk]);
#pragma unroll
    for (int n = 0; n < 4; ++n) bf[n] = *(const bf16x8*)(&Bs[wn + n * 16 + lr][lk]);
#pragma unroll
    for (int m = 0; m < 4; ++m)
#pragma unroll
      for (int n = 0; n < 4; ++n) acc[m][n] = MFMA16(af[m], bf[n], acc[m][n]);
  }

  const int rq = (lane >> 4) * 4;
#pragma unroll
  for (int n = 0; n < 4; ++n) {
    int gcol = n0 + wn + n * 16 + lr;
    float bias = bkv[gcol];
    int c = (gcol >= DIM) ? (gcol - DIM) : gcol;  // gcol % 384
    int h = c >> 5;
    int hd = c & 31;
    short* dst = (gcol < DIM) ? Kws : Vws;
#pragma unroll
    for (int m = 0; m < 4; ++m) {
#pragma unroll
      for (int r = 0; r < 4; ++r) {
        int grow = m0 + wm + m * 16 + rq + r;
        int bb = grow / NTOK;
        int tok = grow - bb * NTOK;
        dst[(((size_t)bb * NHEAD + h) * NTOK + tok) * HDIM + hd] =
            f2bf(acc[m][n][r] + bias);
      }
    }
  }
}

// ---------- kernel 2: fused attention per (b, h) — swapped-QK^T form --------
// 256 threads (R10-proven; 512 thrashed L2, R11). Win-grouped XCD swizzle;
// bf16 bias/mask (halves stream + L2 working set); perm pack; +pos fused.
__global__ __launch_bounds__(256, 3) void attn_kernel(
    const float* __restrict__ x_up, const short* __restrict__ mask_b4,
    const short* __restrict__ bias_b4, const short* __restrict__ Kws,
    const short* __restrict__ Vws, const float* __restrict__ pos,
    short* __restrict__ attn_out) {
  __shared__ short Ksm[NPAD][40];      // K[key][ch], row stride 80B
  __shared__ short Vp[HDIM][NPAD + 8]; // V^T[ch][pi(key)], row stride 720B
  const int bid = blockIdx.x;
  const int xcd = bid & 7;
  const int jj = bid >> 3;                 // 0..191
  const int win = xcd * 8 + jj / 24;       // 0..63, pinned to xcd
  const int rep = jj - (jj / 24) * 24;     // 0..23
  const int h = rep % NHEAD;
  const int b = win + ((rep >= NHEAD) ? 64 : 0);
  const int tid = threadIdx.x;
  const int wave = tid >> 6;
  const int lane = tid & 63;
  const int lr = lane & 15;
  const int lg = lane >> 4;
  const int koff = lg * 8;
  const f32x4 zero4 = {0.f, 0.f, 0.f, 0.f};

  const short* Kb = Kws + ((size_t)b * NHEAD + h) * NTOK * HDIM;
  const short* Vb = Vws + ((size_t)b * NHEAD + h) * NTOK * HDIM;
  {
    const int c8 = (tid & 3) * 8;
    const int rb = tid >> 2;
    const bf16x8 z8 = {0, 0, 0, 0, 0, 0, 0, 0};
#pragma unroll
    for (int r0 = 0; r0 < 384; r0 += 64) {
      int row = r0 + rb;
      if (row < NPAD) {
        bf16x8 kv = z8;
        if (row < NTOK) kv = *(const bf16x8*)(Kb + row * HDIM + c8);
        *(bf16x8*)(&Ksm[row][c8]) = kv;
      }
    }
#pragma unroll
    for (int r0 = 0; r0 < 384; r0 += 64) {
      int row = r0 + rb;
      if (row < NPAD) {
        bf16x8 vv = z8;
        if (row < NTOK) vv = *(const bf16x8*)(Vb + row * HDIM + c8);
        // pi(row): k-slot = ((m&16)>>2) | ((m&12)<<1) | (m&3) within 32-block
        int p = (row & ~31) | ((row & 12) << 1) | ((row & 16) >> 2) | (row & 3);
#pragma unroll
        for (int i = 0; i < 8; ++i) Vp[c8 + i][p] = vv[i];
      }
    }
  }
  __syncthreads();

  for (int qt = 0; qt < 6; ++qt) {
    const int q0 = qt * 64 + wave * 16;
    if (q0 >= NTOK) continue;
    const int qn = q0 + lr;
    const int qidx = (qn < NTOK) ? qn : (NTOK - 1);
    // Q B-frag: col=q=lr, k = channel 8*lg+i (clamped row; invalid cols unused)
    bf16x8 qf;
    {
      const float* qp = x_up + ((size_t)b * NTOK + qidx) * DIM + h * HDIM + koff;
      f32x4 v0 = *(const f32x4*)qp;
      f32x4 v1 = *(const f32x4*)(qp + 4);
#pragma unroll
      for (int i = 0; i < 4; ++i) {
        qf[i] = f2bfrn(v0[i] * SCALE);
        qf[i + 4] = f2bfrn(v1[i] * SCALE);
      }
    }
    // S^T tiles: s[j] = K_j * Q   (A=K: row=key=lr, k=ch; B=Q)
    f32x4 s[22];
    __builtin_amdgcn_s_setprio(1);
#pragma unroll
    for (int j = 0; j < 22; ++j) {
      bf16x8 kf = *(const bf16x8*)(&Ksm[j * 16 + lr][koff]);
      s[j] = MFMA16(kf, qf, zero4);
    }
    __builtin_amdgcn_s_setprio(0);
    // softmax over m: bf16x4 bias+mask loads (8B each, pad handles tail),
    // row max (2 shfls), exp, sum (2 shfls), normalize before bf16 pack.
    const short* bq = bias_b4 + (size_t)h * MG * GSTRIDE + (size_t)lg * GSTRIDE +
                      qidx * 4;
    const short* mq = mask_b4 + (size_t)win * MG * GSTRIDE + (size_t)lg * GSTRIDE +
                      qidx * 4;
    float mx = -1e30f;
#pragma unroll
    for (int j = 0; j < 22; ++j) {
      bf16x4 bv = *(const bf16x4*)(bq + (size_t)j * 4 * GSTRIDE);
      bf16x4 mv = *(const bf16x4*)(mq + (size_t)j * 4 * GSTRIDE);
#pragma unroll
      for (int r = 0; r < 4; ++r) {
        float lv = s[j][r] + bf2f(bv[r]) + bf2f(mv[r]);
        s[j][r] = lv;
        mx = fmaxf(mx, lv);
      }
    }
    mx = fmaxf(mx, __shfl_xor(mx, 16));
    mx = fmaxf(mx, __shfl_xor(mx, 32));
    float sum = 0.f;
#pragma unroll
    for (int j = 0; j < 22; ++j) {
#pragma unroll
      for (int r = 0; r < 4; ++r) {
        float p = __expf(s[j][r] - mx);
        s[j][r] = p;
        sum += p;
      }
    }
    sum += __shfl_xor(sum, 16);
    sum += __shfl_xor(sum, 32);
    const float inv = 1.0f / sum;
    i32x4 up4[11];
#pragma unroll
    for (int j = 0; j < 22; ++j) {
      up4[j >> 1][(j & 1) * 2 + 0] = pack2rn(s[j][0] * inv, s[j][1] * inv);
      up4[j >> 1][(j & 1) * 2 + 1] = pack2rn(s[j][2] * inv, s[j][3] * inv);
    }

    // O^T = V^T_pi * P : A-frag from Vp (b128), B-frag = packed P registers
    f32x4 o0 = zero4;
    f32x4 o1 = zero4;
    __builtin_amdgcn_s_setprio(1);
#pragma unroll
    for (int kt = 0; kt < 11; ++kt) {
      bf16x8 pf = __builtin_bit_cast(bf16x8, up4[kt]);
      bf16x8 a0 = *(const bf16x8*)(&Vp[lr][kt * 32 + koff]);
      bf16x8 a1 = *(const bf16x8*)(&Vp[16 + lr][kt * 32 + koff]);
      o0 = MFMA16(a0, pf, o0);
      o1 = MFMA16(a1, pf, o1);
    }
    __builtin_amdgcn_s_setprio(0);
    // lane holds O[q=lr][d = 4*lg + r (+16)]; O already normalized (P*inv).
    // Add pos_embed (fused), pack+store.
    if (qn < NTOK) {
      const float* pp = pos + ((size_t)b * NTOK + qn) * DIM + h * HDIM + 4 * lg;
      f32x4 p0 = *(const f32x4*)pp;
      f32x4 p1 = *(const f32x4*)(pp + 16);
      short* op = attn_out + ((size_t)b * NTOK + qn) * DIM + h * HDIM + 4 * lg;
      *(int*)(op + 0) = pack2rn(o0[0] + p0[0], o0[1] + p0[1]);
      *(int*)(op + 2) = pack2rn(o0[2] + p0[2], o0[3] + p0[3]);
      *(int*)(op + 16) = pack2rn(o1[0] + p1[0], o1[1] + p1[1]);
      *(int*)(op + 18) = pack2rn(o1[2] + p1[2], o1[3] + p1[3]);
    }
  }
}

// ---------- kernel 3: out = Xa @ w_proj^T + b_proj (Xa = attn+pos, bf16) ----
__global__ __launch_bounds__(256) void out_proj_kernel(
    const short* __restrict__ Xa, const float* __restrict__ W,
    const float* __restrict__ bpr, float* __restrict__ out) {
  __shared__ short As[128][40];
  __shared__ short Bs[128][40];
  const int tid = threadIdx.x;
  const int n0 = blockIdx.x * 128;
  const int m0 = blockIdx.y * 128;
  const int lane = tid & 63;
  const int wave = tid >> 6;
  const int wm = (wave >> 1) * 64;
  const int wn = (wave & 1) * 64;
  const int lr = lane & 15;
  const int lk = (lane >> 4) * 8;
  const int c4 = (tid & 7) * 4;
  const int rbase = tid >> 3;
  const int arow = tid >> 2;
  const int acol8 = (tid & 3) * 8;
  const f32x4 zero4 = {0.f, 0.f, 0.f, 0.f};

  f32x4 acc[4][4];
#pragma unroll
  for (int m = 0; m < 4; ++m)
#pragma unroll
    for (int n = 0; n < 4; ++n) acc[m][n] = zero4;

  for (int kk = 0; kk < 12; ++kk) {
    __syncthreads();
    *(bf16x8*)(&As[arow][acol8]) =
        *(const bf16x8*)(Xa + (size_t)(m0 + arow) * DIM + kk * 32 + acol8);
    *(bf16x8*)(&As[arow + 64][acol8]) =
        *(const bf16x8*)(Xa + (size_t)(m0 + arow + 64) * DIM + kk * 32 + acol8);
#pragma unroll
    for (int i = 0; i < 4; ++i) {
      int row = rbase + i * 32;
      f32x4 v = *(const f32x4*)(W + (size_t)(n0 + row) * DIM + kk * 32 + c4);
      bf16x4 s4;
#pragma unroll
      for (int j = 0; j < 4; ++j) s4[j] = f2bf(v[j]);
      *(bf16x4*)(&Bs[row][c4]) = s4;
    }
    __syncthreads();
    bf16x8 af[4], bf[4];
#pragma unroll
    for (int m = 0; m < 4; ++m) af[m] = *(const bf16x8*)(&As[wm + m * 16 + lr][lk]);
#pragma unroll
    for (int n = 0; n < 4; ++n) bf[n] = *(const bf16x8*)(&Bs[wn + n * 16 + lr][lk]);
#pragma unroll
    for (int m = 0; m < 4; ++m)
#pragma unroll
      for (int n = 0; n < 4; ++n) acc[m][n] = MFMA16(af[m], bf[n], acc[m][n]);
  }

  const int rq = (lane >> 4) * 4;
#pragma unroll
  for (int n = 0; n < 4; ++n) {
    int gcol = n0 + wn + n * 16 + lr;
    float bias = bpr[gcol];
#pragma unroll
    for (int m = 0; m < 4; ++m) {
#pragma unroll
      for (int r = 0; r < 4; ++r) {
        int grow = m0 + wm + m * 16 + rq + r;
        out[(size_t)grow * DIM + gcol] = acc[m][n][r] + bias;
      }
    }
  }
}

extern "C" void kernel_launch(void* const* d_in, const int* in_sizes, int n_in,
                              void* d_out, int out_size, void* d_ws, size_t ws_size,
                              hipStream_t stream) {
  const float* skip = (const float*)d_in[0];
  const float* x_up = (const float*)d_in[1];
  const float* pos = (const float*)d_in[2];
  const float* mask = (const float*)d_in[3];
  const float* w_kv = (const float*)d_in[4];
  const float* b_kv = (const float*)d_in[5];
  const float* w_proj = (const float*)d_in[6];
  const float* b_proj = (const float*)d_in[7];
  const float* bias_table = (const float*)d_in[8];
  const int* rpi = (const int*)d_in[9];
  float* out = (float*)d_out;

  char* ws = (char*)d_ws;
  const size_t kv_bytes = (size_t)BATCH * NHEAD * NTOK * HDIM * 2;   // 33,718,272
  const size_t bias_bytes = (size_t)NHEAD * MG * NTOK * 4 * 2;       //  2,897,664
  const size_t mask_bytes = (size_t)NWIN * MG * NTOK * 4 * 2;        // 15,454,208
  short* Kws = (short*)ws;
  short* Vws = (short*)(ws + kv_bytes);
  short* bias_b4 = (short*)(ws + 2 * kv_bytes);
  short* mask_b4 = (short*)(ws + 2 * kv_bytes + bias_bytes);
  // skip_bf and attn_ws alias: cvt_skip->kv_proj finish before attn writes it
  short* skip_bf = (short*)(ws + 2 * kv_bytes + bias_bytes + mask_bytes);
  short* attn_ws = skip_bf;

  const int bias_total = NHEAD * MG * NTOK * 4;
  const int mask_total = NWIN * MG * NTOK * 4;
  const int n8 = BATCH * NTOK * DIM / 8;  // 2,107,392
  bias_pk_kernel<<<dim3((bias_total + 255) / 256), dim3(256), 0, stream>>>(
      bias_table, rpi, bias_b4);
  mask_pk_kernel<<<dim3((mask_total + 255) / 256), dim3(256), 0, stream>>>(
      mask, mask_b4);
  cvt_skip_kernel<<<dim3((n8 + 255) / 256), dim3(256), 0, stream>>>(
      skip, skip_bf, n8);
  kv_proj_kernel<<<dim3(6, 343), dim3(256), 0, stream>>>(skip_bf, w_kv, b_kv,
                                                         Kws, Vws);
  attn_kernel<<<dim3(BATCH * NHEAD), dim3(256), 0, stream>>>(
      x_up, mask_b4, bias_b4, Kws, Vws, pos, attn_ws);
  out_proj_kernel<<<dim3(3, 343), dim3(256), 0, stream>>>(attn_ws, w_proj,
                                                          b_proj, out);
}

// Round 13
// 279.576 us; speedup vs baseline: 1.4287x; 1.0333x over previous
//
#include <hip/hip_runtime.h>

#define NTOK 343
#define NPAD 352
#define DIM 384
#define NHEAD 12
#define HDIM 32
#define NWIN 64
#define BATCH 128
#define SCALE 0.17677669529663687f
#define LOG2E 1.4426950408889634f
#define SCLG2 (0.17677669529663687f * 1.4426950408889634f)
#define NN 117649   // 343*343
#define MG 88       // NPAD/4 m-groups
#define GSTRIDE 1372  // NTOK*4 elems per m-group

typedef __attribute__((ext_vector_type(8))) short bf16x8;
typedef __attribute__((ext_vector_type(4))) short bf16x4;
typedef __attribute__((ext_vector_type(4))) float f32x4;
typedef __attribute__((ext_vector_type(4))) int i32x4;

static __device__ inline short f2bf(float f) {
  union { float f; unsigned u; } v; v.f = f;
  unsigned r = v.u + 0x7fffu + ((v.u >> 16) & 1u);
  return (short)(r >> 16);
}
static __device__ inline float bf2f(short s) {
  union { unsigned u; float f; } v; v.u = ((unsigned)(unsigned short)s) << 16;
  return v.f;
}
// fast pack: +0x8000 round-to-nearest, v_perm grabs the two high halves (3 VALU).
static __device__ inline int pack2rn(float lo, float hi) {
  union { float f; unsigned u; } a, b;
  a.f = lo; b.f = hi;
  unsigned au = a.u + 0x8000u;
  unsigned bu = b.u + 0x8000u;
  return (int)__builtin_amdgcn_perm(bu, au, 0x07060302u);
}
static __device__ inline short f2bfrn(float f) {
  union { float f; unsigned u; } v; v.f = f;
  return (short)((v.u + 0x8000u) >> 16);
}
// raw v_exp_f32 (exp2) — inputs are pre-scaled by LOG2E in prep kernels
static __device__ inline float fexp2(float x) {
  return __builtin_amdgcn_exp2f(x);
}

#define MFMA16(a, b, c) __builtin_amdgcn_mfma_f32_16x16x32_bf16((a), (b), (c), 0, 0, 0)

// ---- kernel 0a: bias_b4[h][g][q][r] = bf16(LOG2E*table[rpi[q][g*4+r]][h]) ---
__global__ __launch_bounds__(256) void bias_pk_kernel(
    const float* __restrict__ table, const int* __restrict__ rpi,
    short* __restrict__ bias_b4) {
  int idx = blockIdx.x * 256 + threadIdx.x;
  const int total = NHEAD * MG * NTOK * 4;
  if (idx >= total) return;
  int r = idx & 3;
  int t = idx >> 2;
  int q = t % NTOK;
  int u = t / NTOK;
  int g = u % MG;
  int h = u / MG;
  int m = g * 4 + r;
  bias_b4[idx] = (m < NTOK) ? f2bf(table[rpi[q * NTOK + m] * NHEAD + h] * LOG2E)
                            : f2bf(-1e30f);
}

// ---- kernel 0b: mask_b4[w][g][q][r] = bf16(LOG2E*mask[w][q][g*4+r]), pad=0 --
__global__ __launch_bounds__(256) void mask_pk_kernel(
    const float* __restrict__ in, short* __restrict__ mask_b4) {
  int idx = blockIdx.x * 256 + threadIdx.x;
  const int total = NWIN * MG * NTOK * 4;
  if (idx >= total) return;
  int r = idx & 3;
  int t = idx >> 2;
  int q = t % NTOK;
  int u = t / NTOK;
  int g = u % MG;
  int w = u / MG;
  int m = g * 4 + r;
  mask_b4[idx] = (m < NTOK) ? f2bf(in[(size_t)w * NN + q * NTOK + m] * LOG2E) : 0;
}

// ---- kernel 0c: skip f32 -> bf16 (A-operand for kv_proj) -------------------
__global__ __launch_bounds__(256) void cvt_skip_kernel(
    const float* __restrict__ in, short* __restrict__ out, int n8) {
  int i = blockIdx.x * 256 + threadIdx.x;
  if (i >= n8) return;
  f32x4 a = *(const f32x4*)(in + (size_t)i * 8);
  f32x4 b = *(const f32x4*)(in + (size_t)i * 8 + 4);
  bf16x8 o;
#pragma unroll
  for (int j = 0; j < 4; ++j) {
    o[j] = f2bf(a[j]);
    o[j + 4] = f2bf(b[j]);
  }
  *(bf16x8*)(out + (size_t)i * 8) = o;
}

// ---------- kernel 1: kv = skip_bf @ w_kv^T + b_kv -> K_ws/V_ws (bf16) ------
// Linear grid 2058 with bijective same-m0 XCD grouping: the 6 n-tiles sharing
// an A m-tile run on ONE XCD, temporally adjacent -> A re-reads are L2 hits.
__global__ __launch_bounds__(256) void kv_proj_kernel(
    const short* __restrict__ Xbf, const float* __restrict__ W,
    const float* __restrict__ bkv, short* __restrict__ Kws,
    short* __restrict__ Vws) {
  __shared__ short As[128][40];
  __shared__ short Bs[128][40];
  const int L = blockIdx.x;            // 0..2057; XCD = L & 7
  const int xcd = L & 7;
  const int j8 = L >> 3;
  // 2058 = 8*257 + 2 -> xcd 0,1 get 258, others 257 (bijective)
  const int wg = ((xcd < 2) ? xcd * 258 : 516 + (xcd - 2) * 257) + j8;
  const int n0 = (wg % 6) * 128;
  const int m0 = (wg / 6) * 128;
  const int tid = threadIdx.x;
  const int lane = tid & 63;
  const int wave = tid >> 6;
  const int wm = (wave >> 1) * 64;
  const int wn = (wave & 1) * 64;
  const int lr = lane & 15;
  const int lk = (lane >> 4) * 8;
  const int c4 = (tid & 7) * 4;
  const int rbase = tid >> 3;
  const int arow = tid >> 2;        // 0..63
  const int acol8 = (tid & 3) * 8;  // 0,8,16,24
  const f32x4 zero4 = {0.f, 0.f, 0.f, 0.f};

  f32x4 acc[4][4];
#pragma unroll
  for (int m = 0; m < 4; ++m)
#pragma unroll
    for (int n = 0; n < 4; ++n) acc[m][n] = zero4;

  for (int kk = 0; kk < 12; ++kk) {
    __syncthreads();
    *(bf16x8*)(&As[arow][acol8]) =
        *(const bf16x8*)(Xbf + (size_t)(m0 + arow) * DIM + kk * 32 + acol8);
    *(bf16x8*)(&As[arow + 64][acol8]) =
        *(const bf16x8*)(Xbf + (size_t)(m0 + arow + 64) * DIM + kk * 32 + acol8);
#pragma unroll
    for (int i = 0; i < 4; ++i) {
      int row = rbase + i * 32;
      f32x4 v = *(const f32x4*)(W + (size_t)(n0 + row) * DIM + kk * 32 + c4);
      bf16x4 s4;
#pragma unroll
      for (int j = 0; j < 4; ++j) s4[j] = f2bf(v[j]);
      *(bf16x4*)(&Bs[row][c4]) = s4;
    }
    __syncthreads();
    bf16x8 af[4], bf[4];
#pragma unroll
    for (int m = 0; m < 4; ++m) af[m] = *(const bf16x8*)(&As[wm + m * 16 + lr][lk]);
#pragma unroll
    for (int n = 0; n < 4; ++n) bf[n] = *(const bf16x8*)(&Bs[wn + n * 16 + lr][lk]);
#pragma unroll
    for (int m = 0; m < 4; ++m)
#pragma unroll
      for (int n = 0; n < 4; ++n) acc[m][n] = MFMA16(af[m], bf[n], acc[m][n]);
  }

  const int rq = (lane >> 4) * 4;
#pragma unroll
  for (int n = 0; n < 4; ++n) {
    int gcol = n0 + wn + n * 16 + lr;
    float bias = bkv[gcol];
    int c = (gcol >= DIM) ? (gcol - DIM) : gcol;  // gcol % 384
    int h = c >> 5;
    int hd = c & 31;
    short* dst = (gcol < DIM) ? Kws : Vws;
#pragma unroll
    for (int m = 0; m < 4; ++m) {
#pragma unroll
      for (int r = 0; r < 4; ++r) {
        int grow = m0 + wm + m * 16 + rq + r;
        int bb = grow / NTOK;
        int tok = grow - bb * NTOK;
        dst[(((size_t)bb * NHEAD + h) * NTOK + tok) * HDIM + hd] =
            f2bf(acc[m][n][r] + bias);
      }
    }
  }
}

// ---------- kernel 2: fused attention per (b, h) — swapped-QK^T form --------
// 256 threads; win-grouped XCD swizzle; bf16 bias/mask in exp2 domain;
// deferred normalization (P packed unnormalized, O scaled by inv in epilogue).
__global__ __launch_bounds__(256, 3) void attn_kernel(
    const float* __restrict__ x_up, const short* __restrict__ mask_b4,
    const short* __restrict__ bias_b4, const short* __restrict__ Kws,
    const short* __restrict__ Vws, const float* __restrict__ pos,
    short* __restrict__ attn_out) {
  __shared__ short Ksm[NPAD][40];      // K[key][ch], row stride 80B
  __shared__ short Vp[HDIM][NPAD + 8]; // V^T[ch][pi(key)], row stride 720B
  const int bid = blockIdx.x;
  const int xcd = bid & 7;
  const int jj = bid >> 3;                 // 0..191
  const int win = xcd * 8 + jj / 24;       // 0..63, pinned to xcd
  const int rep = jj - (jj / 24) * 24;     // 0..23
  const int h = rep % NHEAD;
  const int b = win + ((rep >= NHEAD) ? 64 : 0);
  const int tid = threadIdx.x;
  const int wave = tid >> 6;
  const int lane = tid & 63;
  const int lr = lane & 15;
  const int lg = lane >> 4;
  const int koff = lg * 8;
  const f32x4 zero4 = {0.f, 0.f, 0.f, 0.f};

  const short* Kb = Kws + ((size_t)b * NHEAD + h) * NTOK * HDIM;
  const short* Vb = Vws + ((size_t)b * NHEAD + h) * NTOK * HDIM;
  {
    const int c8 = (tid & 3) * 8;
    const int rb = tid >> 2;
    const bf16x8 z8 = {0, 0, 0, 0, 0, 0, 0, 0};
#pragma unroll
    for (int r0 = 0; r0 < 384; r0 += 64) {
      int row = r0 + rb;
      if (row < NPAD) {
        bf16x8 kv = z8;
        if (row < NTOK) kv = *(const bf16x8*)(Kb + row * HDIM + c8);
        *(bf16x8*)(&Ksm[row][c8]) = kv;
      }
    }
#pragma unroll
    for (int r0 = 0; r0 < 384; r0 += 64) {
      int row = r0 + rb;
      if (row < NPAD) {
        bf16x8 vv = z8;
        if (row < NTOK) vv = *(const bf16x8*)(Vb + row * HDIM + c8);
        // pi(row): k-slot = ((m&16)>>2) | ((m&12)<<1) | (m&3) within 32-block
        int p = (row & ~31) | ((row & 12) << 1) | ((row & 16) >> 2) | (row & 3);
#pragma unroll
        for (int i = 0; i < 8; ++i) Vp[c8 + i][p] = vv[i];
      }
    }
  }
  __syncthreads();

  for (int qt = 0; qt < 6; ++qt) {
    const int q0 = qt * 64 + wave * 16;
    if (q0 >= NTOK) continue;
    const int qn = q0 + lr;
    const int qidx = (qn < NTOK) ? qn : (NTOK - 1);
    // Q B-frag scaled by SCALE*LOG2E (exp2 domain)
    bf16x8 qf;
    {
      const float* qp = x_up + ((size_t)b * NTOK + qidx) * DIM + h * HDIM + koff;
      f32x4 v0 = *(const f32x4*)qp;
      f32x4 v1 = *(const f32x4*)(qp + 4);
#pragma unroll
      for (int i = 0; i < 4; ++i) {
        qf[i] = f2bfrn(v0[i] * SCLG2);
        qf[i + 4] = f2bfrn(v1[i] * SCLG2);
      }
    }
    // S^T tiles: s[j] = K_j * Q   (A=K: row=key=lr, k=ch; B=Q)
    f32x4 s[22];
    __builtin_amdgcn_s_setprio(1);
#pragma unroll
    for (int j = 0; j < 22; ++j) {
      bf16x8 kf = *(const bf16x8*)(&Ksm[j * 16 + lr][koff]);
      s[j] = MFMA16(kf, qf, zero4);
    }
    __builtin_amdgcn_s_setprio(0);
    // softmax (log2 domain): add bias+mask, row max (2 shfls), p = exp2(lv-mx),
    // pack UNNORMALIZED P (p<=1); normalization deferred to epilogue.
    const short* bq = bias_b4 + (size_t)h * MG * GSTRIDE + (size_t)lg * GSTRIDE +
                      qidx * 4;
    const short* mq = mask_b4 + (size_t)win * MG * GSTRIDE + (size_t)lg * GSTRIDE +
                      qidx * 4;
    float mx = -1e30f;
#pragma unroll
    for (int j = 0; j < 22; ++j) {
      bf16x4 bv = *(const bf16x4*)(bq + (size_t)j * 4 * GSTRIDE);
      bf16x4 mv = *(const bf16x4*)(mq + (size_t)j * 4 * GSTRIDE);
#pragma unroll
      for (int r = 0; r < 4; ++r)
        s[j][r] += bf2f(bv[r]) + bf2f(mv[r]);
      mx = fmaxf(mx, fmaxf(fmaxf(s[j][0], s[j][1]), fmaxf(s[j][2], s[j][3])));
    }
    mx = fmaxf(mx, __shfl_xor(mx, 16));
    mx = fmaxf(mx, __shfl_xor(mx, 32));
    float sum = 0.f;
    i32x4 up4[11];
#pragma unroll
    for (int j = 0; j < 22; ++j) {
      float p0 = fexp2(s[j][0] - mx);
      float p1 = fexp2(s[j][1] - mx);
      float p2 = fexp2(s[j][2] - mx);
      float p3 = fexp2(s[j][3] - mx);
      sum += (p0 + p1) + (p2 + p3);
      up4[j >> 1][(j & 1) * 2 + 0] = pack2rn(p0, p1);
      up4[j >> 1][(j & 1) * 2 + 1] = pack2rn(p2, p3);
    }
    sum += __shfl_xor(sum, 16);
    sum += __shfl_xor(sum, 32);
    const float inv = 1.0f / sum;

    // O^T = V^T_pi * P~ (unnormalized): A-frag from Vp, B-frag = packed P regs
    f32x4 o0 = zero4;
    f32x4 o1 = zero4;
    __builtin_amdgcn_s_setprio(1);
#pragma unroll
    for (int kt = 0; kt < 11; ++kt) {
      bf16x8 pf = __builtin_bit_cast(bf16x8, up4[kt]);
      bf16x8 a0 = *(const bf16x8*)(&Vp[lr][kt * 32 + koff]);
      bf16x8 a1 = *(const bf16x8*)(&Vp[16 + lr][kt * 32 + koff]);
      o0 = MFMA16(a0, pf, o0);
      o1 = MFMA16(a1, pf, o1);
    }
    __builtin_amdgcn_s_setprio(0);
    // O is UNNORMALIZED here (P~ packed before dividing by sum) -> the *inv in
    // the epilogue below is REQUIRED, exactly once. (R9 bug was the opposite.)
    if (qn < NTOK) {
      const float* pp = pos + ((size_t)b * NTOK + qn) * DIM + h * HDIM + 4 * lg;
      f32x4 p0 = *(const f32x4*)pp;
      f32x4 p1 = *(const f32x4*)(pp + 16);
      short* op = attn_out + ((size_t)b * NTOK + qn) * DIM + h * HDIM + 4 * lg;
      *(int*)(op + 0) = pack2rn(o0[0] * inv + p0[0], o0[1] * inv + p0[1]);
      *(int*)(op + 2) = pack2rn(o0[2] * inv + p0[2], o0[3] * inv + p0[3]);
      *(int*)(op + 16) = pack2rn(o1[0] * inv + p1[0], o1[1] * inv + p1[1]);
      *(int*)(op + 18) = pack2rn(o1[2] * inv + p1[2], o1[3] * inv + p1[3]);
    }
  }
}

// ---------- kernel 3: out = Xa @ w_proj^T + b_proj (Xa = attn+pos, bf16) ----
// Linear grid 1029, bijective same-m0 XCD grouping (3 n-tiles share A m-tile).
__global__ __launch_bounds__(256) void out_proj_kernel(
    const short* __restrict__ Xa, const float* __restrict__ W,
    const float* __restrict__ bpr, float* __restrict__ out) {
  __shared__ short As[128][40];
  __shared__ short Bs[128][40];
  const int L = blockIdx.x;            // 0..1028
  const int xcd = L & 7;
  const int j8 = L >> 3;
  // 1029 = 8*128 + 5 -> xcd 0..4 get 129, others 128 (bijective)
  const int wg = ((xcd < 5) ? xcd * 129 : 645 + (xcd - 5) * 128) + j8;
  const int n0 = (wg % 3) * 128;
  const int m0 = (wg / 3) * 128;
  const int tid = threadIdx.x;
  const int lane = tid & 63;
  const int wave = tid >> 6;
  const int wm = (wave >> 1) * 64;
  const int wn = (wave & 1) * 64;
  const int lr = lane & 15;
  const int lk = (lane >> 4) * 8;
  const int c4 = (tid & 7) * 4;
  const int rbase = tid >> 3;
  const int arow = tid >> 2;
  const int acol8 = (tid & 3) * 8;
  const f32x4 zero4 = {0.f, 0.f, 0.f, 0.f};

  f32x4 acc[4][4];
#pragma unroll
  for (int m = 0; m < 4; ++m)
#pragma unroll
    for (int n = 0; n < 4; ++n) acc[m][n] = zero4;

  for (int kk = 0; kk < 12; ++kk) {
    __syncthreads();
    *(bf16x8*)(&As[arow][acol8]) =
        *(const bf16x8*)(Xa + (size_t)(m0 + arow) * DIM + kk * 32 + acol8);
    *(bf16x8*)(&As[arow + 64][acol8]) =
        *(const bf16x8*)(Xa + (size_t)(m0 + arow + 64) * DIM + kk * 32 + acol8);
#pragma unroll
    for (int i = 0; i < 4; ++i) {
      int row = rbase + i * 32;
      f32x4 v = *(const f32x4*)(W + (size_t)(n0 + row) * DIM + kk * 32 + c4);
      bf16x4 s4;
#pragma unroll
      for (int j = 0; j < 4; ++j) s4[j] = f2bf(v[j]);
      *(bf16x4*)(&Bs[row][c4]) = s4;
    }
    __syncthreads();
    bf16x8 af[4], bf[4];
#pragma unroll
    for (int m = 0; m < 4; ++m) af[m] = *(const bf16x8*)(&As[wm + m * 16 + lr][lk]);
#pragma unroll
    for (int n = 0; n < 4; ++n) bf[n] = *(const bf16x8*)(&Bs[wn + n * 16 + lr][lk]);
#pragma unroll
    for (int m = 0; m < 4; ++m)
#pragma unroll
      for (int n = 0; n < 4; ++n) acc[m][n] = MFMA16(af[m], bf[n], acc[m][n]);
  }

  const int rq = (lane >> 4) * 4;
#pragma unroll
  for (int n = 0; n < 4; ++n) {
    int gcol = n0 + wn + n * 16 + lr;
    float bias = bpr[gcol];
#pragma unroll
    for (int m = 0; m < 4; ++m) {
#pragma unroll
      for (int r = 0; r < 4; ++r) {
        int grow = m0 + wm + m * 16 + rq + r;
        out[(size_t)grow * DIM + gcol] = acc[m][n][r] + bias;
      }
    }
  }
}

extern "C" void kernel_launch(void* const* d_in, const int* in_sizes, int n_in,
                              void* d_out, int out_size, void* d_ws, size_t ws_size,
                              hipStream_t stream) {
  const float* skip = (const float*)d_in[0];
  const float* x_up = (const float*)d_in[1];
  const float* pos = (const float*)d_in[2];
  const float* mask = (const float*)d_in[3];
  const float* w_kv = (const float*)d_in[4];
  const float* b_kv = (const float*)d_in[5];
  const float* w_proj = (const float*)d_in[6];
  const float* b_proj = (const float*)d_in[7];
  const float* bias_table = (const float*)d_in[8];
  const int* rpi = (const int*)d_in[9];
  float* out = (float*)d_out;

  char* ws = (char*)d_ws;
  const size_t kv_bytes = (size_t)BATCH * NHEAD * NTOK * HDIM * 2;   // 33,718,272
  const size_t bias_bytes = (size_t)NHEAD * MG * NTOK * 4 * 2;       //  2,897,664
  const size_t mask_bytes = (size_t)NWIN * MG * NTOK * 4 * 2;        // 15,454,208
  short* Kws = (short*)ws;
  short* Vws = (short*)(ws + kv_bytes);
  short* bias_b4 = (short*)(ws + 2 * kv_bytes);
  short* mask_b4 = (short*)(ws + 2 * kv_bytes + bias_bytes);
  // skip_bf and attn_ws alias: cvt_skip->kv_proj finish before attn writes it
  short* skip_bf = (short*)(ws + 2 * kv_bytes + bias_bytes + mask_bytes);
  short* attn_ws = skip_bf;

  const int bias_total = NHEAD * MG * NTOK * 4;
  const int mask_total = NWIN * MG * NTOK * 4;
  const int n8 = BATCH * NTOK * DIM / 8;  // 2,107,392
  bias_pk_kernel<<<dim3((bias_total + 255) / 256), dim3(256), 0, stream>>>(
      bias_table, rpi, bias_b4);
  mask_pk_kernel<<<dim3((mask_total + 255) / 256), dim3(256), 0, stream>>>(
      mask, mask_b4);
  cvt_skip_kernel<<<dim3((n8 + 255) / 256), dim3(256), 0, stream>>>(
      skip, skip_bf, n8);
  kv_proj_kernel<<<dim3(2058), dim3(256), 0, stream>>>(skip_bf, w_kv, b_kv,
                                                       Kws, Vws);
  attn_kernel<<<dim3(BATCH * NHEAD), dim3(256), 0, stream>>>(
      x_up, mask_b4, bias_b4, Kws, Vws, pos, attn_ws);
  out_proj_kernel<<<dim3(1029), dim3(256), 0, stream>>>(attn_ws, w_proj,
                                                        b_proj, out);
}